// Round 22
// baseline (101.030 us; speedup 1.0000x reference)
//
#include <hip/hip_runtime.h>
#include <hip/hip_bf16.h>

typedef float f32x4 __attribute__((ext_vector_type(4)));
typedef __bf16 bf16x8 __attribute__((ext_vector_type(8)));
typedef __bf16 bf16x4 __attribute__((ext_vector_type(4)));
typedef short s16x4 __attribute__((ext_vector_type(4)));

constexpr int C = 256;
constexpr int N = 2304;           // 48*48 tokens per batch
constexpr int T = 2 * N;          // total tokens

#if __has_builtin(__builtin_amdgcn_exp2f)
#define EXP2F(x) __builtin_amdgcn_exp2f(x)
#else
#define EXP2F(x) exp2f(x)
#endif

__device__ __forceinline__ bf16x8 load_bf8(const __bf16* p) {
    return *reinterpret_cast<const bf16x8*>(p);
}

__device__ __forceinline__ f32x4 mfma32(bf16x8 a, bf16x8 b, f32x4 c) {
    return __builtin_amdgcn_mfma_f32_16x16x32_bf16(a, b, c, 0, 0, 0);
}

// K=16 MFMA: 4-element k-granules match the QK^T C/D output layout, so P feeds
// PV entirely in-register (no LDS redistribution). Verified correct R4-R21.
#if __has_builtin(__builtin_amdgcn_mfma_f32_16x16x16bf16_1k)
__device__ __forceinline__ f32x4 mfma16(bf16x4 a, bf16x4 b, f32x4 c) {
    return __builtin_amdgcn_mfma_f32_16x16x16bf16_1k(
        __builtin_bit_cast(s16x4, a), __builtin_bit_cast(s16x4, b), c, 0, 0, 0);
}
#else
__device__ __forceinline__ f32x4 mfma16(bf16x4 a, bf16x4 b, f32x4 c) {
    f32x4 d;
    asm volatile("v_mfma_f32_16x16x16_bf16 %0, %1, %2, %3"
                 : "=v"(d) : "v"(a), "v"(b), "v"(c));
    return d;
}
#endif

// async global->LDS, 16B per lane; dest = wave-uniform base + lane*16
__device__ __forceinline__ void gload_lds16(const __bf16* g, __bf16* l) {
    __builtin_amdgcn_global_load_lds(
        (const __attribute__((address_space(1))) void*)g,
        (__attribute__((address_space(3))) void*)l, 16, 0, 0);
}

#define VMCNT2() asm volatile("s_waitcnt vmcnt(2)" ::: "memory")
#define VMCNT0() asm volatile("s_waitcnt vmcnt(0)" ::: "memory")
#define LGKM0()  asm volatile("s_waitcnt lgkmcnt(0)" ::: "memory")

// ---------------- kernel A: fused weight-convert + gate/transpose ----------------
__global__ void prep_kernel(const float* __restrict__ x, const float* __restrict__ u,
                            const float* __restrict__ Wg, const float* __restrict__ bg,
                            const float* __restrict__ Wq, const float* __restrict__ Wk,
                            const float* __restrict__ Wv, const float* __restrict__ Wo,
                            __bf16* __restrict__ xT, __bf16* __restrict__ gxT,
                            __bf16* __restrict__ Wb) {
    __shared__ float tile[32][65];
    int t = threadIdx.x;
    if (blockIdx.x >= 576) {
        int u2 = blockIdx.x - 576;          // [0,256)
        const float* srcs[4] = {Wq, Wk, Wv, Wo};
        int m = u2 >> 6;
        int idx = (u2 & 63) * 256 + t;      // [0, 16384)
        float4 v = reinterpret_cast<const float4*>(srcs[m])[idx];
        bf16x4 o = { (__bf16)v.x, (__bf16)v.y, (__bf16)v.z, (__bf16)v.w };
        reinterpret_cast<bf16x4*>(Wb + m * 65536)[idx] = o;
        return;
    }
    int uu = blockIdx.x;                    // [0,576)
    int n0 = (uu % 36) * 64;
    int c0 = ((uu / 36) & 7) * 32;
    int b = uu / 288;
    const float* xp = x + (b * C + c0) * N + n0;
    #pragma unroll
    for (int rr = 0; rr < 8; ++rr) {
        int cl = rr * 4 + (t >> 6);
        int nl = t & 63;
        tile[cl][nl] = xp[cl * N + nl];
    }
    __syncthreads();
    int cq = (t & 7) * 4;
    #pragma unroll
    for (int it = 0; it < 2; ++it) {
        int nl = it * 32 + (t >> 3);
        float uv = u[b * N + n0 + nl];
        bf16x4 xo, go;
        #pragma unroll
        for (int jj = 0; jj < 4; ++jj) {
            int cch = c0 + cq + jj;
            float xv = tile[cq + jj][nl];
            float gate = 1.0f - (Wg[cch] * uv + bg[cch]);
            xo[jj] = (__bf16)xv;
            go[jj] = (__bf16)(xv * gate);
        }
        int tok = b * N + n0 + nl;
        *reinterpret_cast<bf16x4*>(xT + (long)tok * C + c0 + cq) = xo;
        *reinterpret_cast<bf16x4*>(gxT + (long)tok * C + c0 + cq) = go;
    }
}

// ---------------- kernel 2: QKV projections, head-pinned (R19 version) ----------------
__global__ __launch_bounds__(256) void qkv_kernel(const __bf16* __restrict__ Wb,
    const __bf16* __restrict__ xT, const __bf16* __restrict__ gxT,
    const float* __restrict__ bq, const float* __restrict__ bk, const float* __restrict__ bv,
    const float* __restrict__ u,
    __bf16* __restrict__ Q, __bf16* __restrict__ K, __bf16* __restrict__ V) {
    int L = blockIdx.x;               // 864 = 8 heads * 36 chunks * 3 proj
    int h = L & 7;
    int rest = L >> 3;                // [0,108)
    int c = rest % 36;
    int z = rest / 36;                // 0=q,1=k,2=v
    int wave = threadIdx.x >> 6, lane = threadIdx.x & 63;
    int g = lane >> 4, r = lane & 15;
    int ow = h * 32 + (wave & 1) * 16;        // global output channel base
    int t0 = c * 128 + (wave >> 1) * 64;      // token base (64 tokens/wave)
    const __bf16* W = Wb + z * 65536;
    const __bf16* inp = (z == 2) ? xT : gxT;
    f32x4 acc[4] = {};
    for (int k = 0; k < 8; ++k) {
        bf16x8 a = load_bf8(W + (ow + r) * C + k * 32 + g * 8);
        #pragma unroll
        for (int tb = 0; tb < 4; ++tb) {
            bf16x8 bfr = load_bf8(inp + (long)(t0 + tb * 16 + r) * C + k * 32 + g * 8);
            acc[tb] = mfma32(a, bfr, acc[tb]);
        }
    }
    const float* bias = (z == 0) ? bq : (z == 1) ? bk : bv;
    float bvw[4];
    #pragma unroll
    for (int i = 0; i < 4; ++i) bvw[i] = bias[ow + g * 4 + i];
    int d0 = (wave & 1) * 16 + g * 4;         // channel-within-head
    const float SC = 0.17677669529663687f * 1.4426950408889634f;  // SCALE * log2(e)
    #pragma unroll
    for (int tb = 0; tb < 4; ++tb) {
        int t = t0 + tb * 16 + r;
        int b = t / N, n = t % N;
        if (z == 2) {
            #pragma unroll
            for (int i = 0; i < 4; ++i)
                V[((long)(b * 8 + h) * 32 + d0 + i) * N + n] = (__bf16)(acc[tb][i] + bvw[i]);
        } else {
            bf16x4 outv;
            if (z == 1) {
                float scale = SC * (1.0f - u[t]);
                #pragma unroll
                for (int i = 0; i < 4; ++i) outv[i] = (__bf16)((acc[tb][i] + bvw[i]) * scale);
            } else {
                #pragma unroll
                for (int i = 0; i < 4; ++i) outv[i] = (__bf16)(acc[tb][i] + bvw[i]);
            }
            __bf16* dst = (z == 0) ? Q : K;
            *reinterpret_cast<bf16x4*>(dst + ((long)(b * 8 + h) * N + n) * 32 + d0) = outv;
        }
    }
}

// ---------------- kernel 3: flash attention (R20 structure, INTERNAL 2x REPEAT) ----------------
// MEASUREMENT ROUND: body repeats REP=2 (re-stage, recompute, same output) so
// this dispatch (~64us) tops the rocprof table and we get counters for the
// BEST-KNOWN structure (R20: dual 4-share groups, 576x512). attn_true =
// total - 68.6. REVERTS to REP=1 next round.
__global__ __launch_bounds__(512) void attn_kernel(const __bf16* __restrict__ Q,
    const __bf16* __restrict__ K, const __bf16* __restrict__ V,
    __bf16* __restrict__ aoT) {
    __shared__ __bf16 sMem[16384];   // 32KB: group g owns [g*8192, +8192)
    int id = blockIdx.x;             // 576 = 8 xcd * 72
    int xcd = id & 7, j = id >> 3;   // j in [0,72)
    int bh = xcd + 8 * (j / 36);
    int qblk = j % 36;
    int tid = threadIdx.x;
    int wave = tid >> 6, lane = tid & 63;
    int grp = wave >> 2, wv = wave & 3;
    int g = lane >> 4, r = lane & 15;
    int q0w = qblk * 64 + wv * 16;
    const __bf16* Qg = Q + (long)bh * N * 32;
    const __bf16* Kg = K + (long)bh * N * 32 + (long)grp * 1152 * 32;
    const __bf16* Vg = V + (long)bh * 32 * N + grp * 1152;
    bf16x8 qf = load_bf8(Qg + (q0w + r) * 32 + g * 8);   // B-frag: Q^T[d][q]
    int s_ = (wv << 6) | lane;                 // 0..255 within group
    int l_ = s_ ^ ((s_ >> 3) & 7);
    const __bf16* kS = Kg + (l_ >> 2) * 32 + (l_ & 3) * 8;        // + m0*32
    const __bf16* vS = Vg + (long)(l_ >> 3) * N + (l_ & 7) * 8;   // + m0
    __bf16* kB = sMem + grp * 8192;        // K bufs: 2 x 2048 elems
    __bf16* vB = kB + 4096;                // V bufs: 2 x 2048 elems
    int so = wv * 512;                     // wave staging base within tile
    auto STAGE = [&](long m0, int buf) {
        gload_lds16(kS + m0 * 32, kB + buf * 2048 + so);
        gload_lds16(vS + m0,      vB + buf * 2048 + so);
    };
    int pk[4], pvo[4][2];
    #pragma unroll
    for (int t = 0; t < 4; ++t) {
        int ck = (t * 16 + r) * 4 + g;
        pk[t] = (ck ^ ((ck >> 3) & 7)) * 8;
        #pragma unroll
        for (int dt = 0; dt < 2; ++dt) {
            int cv = (dt * 16 + r) * 8 + t * 2 + (g >> 1);
            pvo[t][dt] = (cv ^ ((cv >> 3) & 7)) * 8 + (g & 1) * 4;
        }
    }
    bf16x4 onesv;
    #pragma unroll
    for (int i = 0; i < 4; ++i) onesv[i] = (__bf16)1.0f;
    for (int rep = 0; rep < 2; ++rep) {
        if (rep) __syncthreads();            // epilogue reads of sMem drained
        f32x4 oa0 = {}, oa1 = {}, oal = {};
        STAGE(0, 0);
        STAGE(64, 1);
        for (int t = 0; t < 18; ++t) {
            if (t < 17) { VMCNT2(); } else { VMCNT0(); }
            __builtin_amdgcn_s_barrier();        // tile t landed for all waves
            const __bf16* kb = kB + (t & 1) * 2048;
            const __bf16* vb = vB + (t & 1) * 2048;
            bf16x8 kc0 = load_bf8(kb + pk[0]);
            bf16x8 kc1 = load_bf8(kb + pk[1]);
            bf16x8 kc2 = load_bf8(kb + pk[2]);
            bf16x8 kc3 = load_bf8(kb + pk[3]);
            bf16x4 vf[4][2];
            #pragma unroll
            for (int tt = 0; tt < 4; ++tt)
                #pragma unroll
                for (int dt = 0; dt < 2; ++dt)
                    vf[tt][dt] = *reinterpret_cast<const bf16x4*>(vb + pvo[tt][dt]);
            f32x4 z = {};
            __builtin_amdgcn_s_setprio(1);
            f32x4 s0 = mfma32(kc0, qf, z);   // S^T: lane(g,r) q=r, m=tt*16+g*4+i
            f32x4 s1 = mfma32(kc1, qf, z);
            f32x4 s2 = mfma32(kc2, qf, z);
            f32x4 s3 = mfma32(kc3, qf, z);
            __builtin_amdgcn_s_setprio(0);
            bf16x4 pa0, pa1, pa2, pa3;
            #pragma unroll
            for (int i = 0; i < 4; ++i) pa0[i] = (__bf16)EXP2F(s0[i]);
            #pragma unroll
            for (int i = 0; i < 4; ++i) pa1[i] = (__bf16)EXP2F(s1[i]);
            #pragma unroll
            for (int i = 0; i < 4; ++i) pa2[i] = (__bf16)EXP2F(s2[i]);
            #pragma unroll
            for (int i = 0; i < 4; ++i) pa3[i] = (__bf16)EXP2F(s3[i]);
            __builtin_amdgcn_s_setprio(1);
            oa0 = mfma16(vf[0][0], pa0, oa0);
            oa1 = mfma16(vf[0][1], pa0, oa1);
            oal = mfma16(onesv,    pa0, oal);
            oa0 = mfma16(vf[1][0], pa1, oa0);
            oa1 = mfma16(vf[1][1], pa1, oa1);
            oal = mfma16(onesv,    pa1, oal);
            oa0 = mfma16(vf[2][0], pa2, oa0);
            oa1 = mfma16(vf[2][1], pa2, oa1);
            oal = mfma16(onesv,    pa2, oal);
            oa0 = mfma16(vf[3][0], pa3, oa0);
            oa1 = mfma16(vf[3][1], pa3, oa1);
            oal = mfma16(onesv,    pa3, oal);
            __builtin_amdgcn_s_setprio(0);
            LGKM0();                             // my reads of this buffer done
            __builtin_amdgcn_s_barrier();        // everyone's reads done
            if (t < 16)                          // refill the buffer just consumed
                STAGE((long)(t + 2) * 64, t & 1);
        }
        // ---- combine the two key-halves via retired staging LDS ----
        __syncthreads();
        float* F = reinterpret_cast<float*>(sMem);
        float* D = F + 4096;
        int fb = (grp * 4 + wv) * 512 + r * 32;
        int sg = g ^ (r & 7);
        *reinterpret_cast<f32x4*>(F + fb + sg * 4) = oa0;
        *reinterpret_cast<f32x4*>(F + fb + (sg ^ 4) * 4) = oa1;
        if (g == 0) D[grp * 64 + wv * 16 + r] = oal[0];
        __syncthreads();
        {
            int q = tid >> 3;            // 0..63
            int dg = tid & 7;            // d-granule -> d4 = dg*4
            int qw = q >> 4, qq = q & 15;
            int off = qw * 512 + qq * 32 + ((dg ^ (qq & 7)) * 4);
            f32x4 sum = *reinterpret_cast<const f32x4*>(F + off) +
                        *reinterpret_cast<const f32x4*>(F + 2048 + off);
            float l = D[qw * 16 + qq] + D[64 + qw * 16 + qq];
            float inv = 1.0f / l;
            bf16x4 ov;
            #pragma unroll
            for (int i = 0; i < 4; ++i) ov[i] = (__bf16)(sum[i] * inv);
            int b = bh >> 3, h = bh & 7;
            *reinterpret_cast<bf16x4*>(
                aoT + (long)(b * N + qblk * 64 + q) * C + h * 32 + dg * 4) = ov;
        }
    }
}

// ---------------- kernel 4: output projection + bias + residual ----------------
__global__ __launch_bounds__(256) void outp_kernel(const __bf16* __restrict__ Wb,
    const __bf16* __restrict__ aoT, const float* __restrict__ bo,
    const float* __restrict__ x, float* __restrict__ out) {
    int o0 = blockIdx.y * 64;
    int t0 = blockIdx.x * 16;
    int wave = threadIdx.x >> 6, lane = threadIdx.x & 63;
    int g = lane >> 4, r = lane & 15;
    int ow = o0 + wave * 16;
    const __bf16* W = Wb + 3 * 65536;   // Wo
    f32x4 acc = {};
    for (int k = 0; k < 8; ++k) {
        bf16x8 a = load_bf8(W + (ow + r) * C + k * 32 + g * 8);
        bf16x8 bfr = load_bf8(aoT + (long)(t0 + r) * C + k * 32 + g * 8);
        acc = mfma32(a, bfr, acc);
    }
    float bvw[4];
    #pragma unroll
    for (int i = 0; i < 4; ++i) bvw[i] = bo[ow + g * 4 + i];
    int t = t0 + r;
    int b = t / N, n = t % N;
    #pragma unroll
    for (int i = 0; i < 4; ++i) {
        long idx = ((long)b * C + ow + g * 4 + i) * N + n;
        out[idx] = acc[i] + bvw[i] + x[idx];
    }
}

extern "C" void kernel_launch(void* const* d_in, const int* in_sizes, int n_in,
                              void* d_out, int out_size, void* d_ws, size_t ws_size,
                              hipStream_t stream) {
    const float* x  = (const float*)d_in[0];
    const float* u  = (const float*)d_in[1];
    const float* Wq = (const float*)d_in[2];
    const float* bq = (const float*)d_in[3];
    const float* Wk = (const float*)d_in[4];
    const float* bk = (const float*)d_in[5];
    const float* Wv = (const float*)d_in[6];
    const float* bv = (const float*)d_in[7];
    const float* Wg = (const float*)d_in[8];
    const float* bg = (const float*)d_in[9];
    const float* Wo = (const float*)d_in[10];
    const float* bo = (const float*)d_in[11];
    float* out = (float*)d_out;

    char* ws = (char*)d_ws;
    size_t off = 0;
    auto alloc = [&](size_t bytes) {
        char* p = ws + off;
        off += (bytes + 255) & ~(size_t)255;
        return p;
    };
    __bf16* Wb  = (__bf16*)alloc((size_t)4 * 65536 * 2);
    __bf16* xT  = (__bf16*)alloc((size_t)T * C * 2);
    __bf16* gxT = (__bf16*)alloc((size_t)T * C * 2);
    __bf16* Qb  = (__bf16*)alloc((size_t)16 * N * 32 * 2);
    __bf16* Kb  = (__bf16*)alloc((size_t)16 * N * 32 * 2);
    __bf16* Vb  = (__bf16*)alloc((size_t)16 * N * 32 * 2);
    __bf16* aoT = (__bf16*)alloc((size_t)T * C * 2);

    prep_kernel<<<832, 256, 0, stream>>>(x, u, Wg, bg, Wq, Wk, Wv, Wo, xT, gxT, Wb);
    qkv_kernel<<<864, 256, 0, stream>>>(Wb, xT, gxT, bq, bk, bv, u, Qb, Kb, Vb);
    attn_kernel<<<576, 512, 0, stream>>>(Qb, Kb, Vb, aoT);
    outp_kernel<<<dim3(288, 4), 256, 0, stream>>>(Wb, aoT, bo, x, out);
}

// Round 23
// 67.321 us; speedup vs baseline: 1.5007x; 1.5007x over previous
//
#include <hip/hip_runtime.h>
#include <hip/hip_bf16.h>

typedef float f32x4 __attribute__((ext_vector_type(4)));
typedef __bf16 bf16x8 __attribute__((ext_vector_type(8)));
typedef __bf16 bf16x4 __attribute__((ext_vector_type(4)));
typedef short s16x4 __attribute__((ext_vector_type(4)));

constexpr int C = 256;
constexpr int N = 2304;           // 48*48 tokens per batch
constexpr int T = 2 * N;          // total tokens

#if __has_builtin(__builtin_amdgcn_exp2f)
#define EXP2F(x) __builtin_amdgcn_exp2f(x)
#else
#define EXP2F(x) exp2f(x)
#endif

__device__ __forceinline__ bf16x8 load_bf8(const __bf16* p) {
    return *reinterpret_cast<const bf16x8*>(p);
}

__device__ __forceinline__ f32x4 mfma32(bf16x8 a, bf16x8 b, f32x4 c) {
    return __builtin_amdgcn_mfma_f32_16x16x32_bf16(a, b, c, 0, 0, 0);
}

// K=16 MFMA: 4-element k-granules match the QK^T C/D output layout, so P feeds
// PV entirely in-register (no LDS redistribution). Verified correct R4-R22.
#if __has_builtin(__builtin_amdgcn_mfma_f32_16x16x16bf16_1k)
__device__ __forceinline__ f32x4 mfma16(bf16x4 a, bf16x4 b, f32x4 c) {
    return __builtin_amdgcn_mfma_f32_16x16x16bf16_1k(
        __builtin_bit_cast(s16x4, a), __builtin_bit_cast(s16x4, b), c, 0, 0, 0);
}
#else
__device__ __forceinline__ f32x4 mfma16(bf16x4 a, bf16x4 b, f32x4 c) {
    f32x4 d;
    asm volatile("v_mfma_f32_16x16x16_bf16 %0, %1, %2, %3"
                 : "=v"(d) : "v"(a), "v"(b), "v"(c));
    return d;
}
#endif

// async global->LDS, 16B per lane; dest = wave-uniform base + lane*16
__device__ __forceinline__ void gload_lds16(const __bf16* g, __bf16* l) {
    __builtin_amdgcn_global_load_lds(
        (const __attribute__((address_space(1))) void*)g,
        (__attribute__((address_space(3))) void*)l, 16, 0, 0);
}

#define VMCNT2() asm volatile("s_waitcnt vmcnt(2)" ::: "memory")
#define VMCNT0() asm volatile("s_waitcnt vmcnt(0)" ::: "memory")
#define LGKM0()  asm volatile("s_waitcnt lgkmcnt(0)" ::: "memory")

// ---------------- kernel A: fused weight-convert + gate/transpose ----------------
__global__ void prep_kernel(const float* __restrict__ x, const float* __restrict__ u,
                            const float* __restrict__ Wg, const float* __restrict__ bg,
                            const float* __restrict__ Wq, const float* __restrict__ Wk,
                            const float* __restrict__ Wv, const float* __restrict__ Wo,
                            __bf16* __restrict__ xT, __bf16* __restrict__ gxT,
                            __bf16* __restrict__ Wb) {
    __shared__ float tile[32][65];
    int t = threadIdx.x;
    if (blockIdx.x >= 576) {
        int u2 = blockIdx.x - 576;          // [0,256)
        const float* srcs[4] = {Wq, Wk, Wv, Wo};
        int m = u2 >> 6;
        int idx = (u2 & 63) * 256 + t;      // [0, 16384)
        float4 v = reinterpret_cast<const float4*>(srcs[m])[idx];
        bf16x4 o = { (__bf16)v.x, (__bf16)v.y, (__bf16)v.z, (__bf16)v.w };
        reinterpret_cast<bf16x4*>(Wb + m * 65536)[idx] = o;
        return;
    }
    int uu = blockIdx.x;                    // [0,576)
    int n0 = (uu % 36) * 64;
    int c0 = ((uu / 36) & 7) * 32;
    int b = uu / 288;
    const float* xp = x + (b * C + c0) * N + n0;
    #pragma unroll
    for (int rr = 0; rr < 8; ++rr) {
        int cl = rr * 4 + (t >> 6);
        int nl = t & 63;
        tile[cl][nl] = xp[cl * N + nl];
    }
    __syncthreads();
    int cq = (t & 7) * 4;
    #pragma unroll
    for (int it = 0; it < 2; ++it) {
        int nl = it * 32 + (t >> 3);
        float uv = u[b * N + n0 + nl];
        bf16x4 xo, go;
        #pragma unroll
        for (int jj = 0; jj < 4; ++jj) {
            int cch = c0 + cq + jj;
            float xv = tile[cq + jj][nl];
            float gate = 1.0f - (Wg[cch] * uv + bg[cch]);
            xo[jj] = (__bf16)xv;
            go[jj] = (__bf16)(xv * gate);
        }
        int tok = b * N + n0 + nl;
        *reinterpret_cast<bf16x4*>(xT + (long)tok * C + c0 + cq) = xo;
        *reinterpret_cast<bf16x4*>(gxT + (long)tok * C + c0 + cq) = go;
    }
}

// ---------------- kernel 2: QKV projections, head-pinned (R19 version) ----------------
__global__ __launch_bounds__(256) void qkv_kernel(const __bf16* __restrict__ Wb,
    const __bf16* __restrict__ xT, const __bf16* __restrict__ gxT,
    const float* __restrict__ bq, const float* __restrict__ bk, const float* __restrict__ bv,
    const float* __restrict__ u,
    __bf16* __restrict__ Q, __bf16* __restrict__ K, __bf16* __restrict__ V) {
    int L = blockIdx.x;               // 864 = 8 heads * 36 chunks * 3 proj
    int h = L & 7;
    int rest = L >> 3;                // [0,108)
    int c = rest % 36;
    int z = rest / 36;                // 0=q,1=k,2=v
    int wave = threadIdx.x >> 6, lane = threadIdx.x & 63;
    int g = lane >> 4, r = lane & 15;
    int ow = h * 32 + (wave & 1) * 16;        // global output channel base
    int t0 = c * 128 + (wave >> 1) * 64;      // token base (64 tokens/wave)
    const __bf16* W = Wb + z * 65536;
    const __bf16* inp = (z == 2) ? xT : gxT;
    f32x4 acc[4] = {};
    for (int k = 0; k < 8; ++k) {
        bf16x8 a = load_bf8(W + (ow + r) * C + k * 32 + g * 8);
        #pragma unroll
        for (int tb = 0; tb < 4; ++tb) {
            bf16x8 bfr = load_bf8(inp + (long)(t0 + tb * 16 + r) * C + k * 32 + g * 8);
            acc[tb] = mfma32(a, bfr, acc[tb]);
        }
    }
    const float* bias = (z == 0) ? bq : (z == 1) ? bk : bv;
    float bvw[4];
    #pragma unroll
    for (int i = 0; i < 4; ++i) bvw[i] = bias[ow + g * 4 + i];
    int d0 = (wave & 1) * 16 + g * 4;         // channel-within-head
    const float SC = 0.17677669529663687f * 1.4426950408889634f;  // SCALE * log2(e)
    #pragma unroll
    for (int tb = 0; tb < 4; ++tb) {
        int t = t0 + tb * 16 + r;
        int b = t / N, n = t % N;
        if (z == 2) {
            #pragma unroll
            for (int i = 0; i < 4; ++i)
                V[((long)(b * 8 + h) * 32 + d0 + i) * N + n] = (__bf16)(acc[tb][i] + bvw[i]);
        } else {
            bf16x4 outv;
            if (z == 1) {
                float scale = SC * (1.0f - u[t]);
                #pragma unroll
                for (int i = 0; i < 4; ++i) outv[i] = (__bf16)((acc[tb][i] + bvw[i]) * scale);
            } else {
                #pragma unroll
                for (int i = 0; i < 4; ++i) outv[i] = (__bf16)(acc[tb][i] + bvw[i]);
            }
            __bf16* dst = (z == 0) ? Q : K;
            *reinterpret_cast<bf16x4*>(dst + ((long)(b * 8 + h) * N + n) * 32 + d0) = outv;
        }
    }
}

// ---------------- kernel 3: flash attention (key-split blocks, global partials) ----------------
// R22 counters: Occ 25%, VALU 37%, Mfma 25% -> imbalance/latency-bound at
// 2.25 blocks/CU. This round: 1152 x 256thr blocks = (head, 64q, KEY-HALF);
// one 4-share group per block (volume lever preserved), 18 iters over 1152
// keys. No in-kernel combine: f32 partials + per-head denominators go to
// global; outp folds the combine. Blocks/CU 4.5 -> makespan 1.11x.
__global__ __launch_bounds__(256) void attn_kernel(const __bf16* __restrict__ Q,
    const __bf16* __restrict__ K, const __bf16* __restrict__ V,
    float* __restrict__ PO, float* __restrict__ DO_) {
    __shared__ __bf16 sMem[8192];    // 16KB: K dbuf 2x2048 + V dbuf 2x2048
    int id = blockIdx.x;             // 1152 = 8 xcd * 144
    int xcd = id & 7, j = id >> 3;   // j in [0,144)
    int b = j / 72;
    int jj = j % 72;
    int qblk = jj >> 1, half = jj & 1;
    int bh = xcd + 8 * b;
    int h = xcd;
    int tid = threadIdx.x;
    int wave = tid >> 6, lane = tid & 63;
    int g = lane >> 4, r = lane & 15;
    int q0w = qblk * 64 + wave * 16;
    const __bf16* Qg = Q + (long)bh * N * 32;
    const __bf16* Kg = K + (long)bh * N * 32 + (long)half * 1152 * 32;
    const __bf16* Vg = V + (long)bh * 32 * N + half * 1152;
    bf16x8 qf = load_bf8(Qg + (q0w + r) * 32 + g * 8);   // B-frag: Q^T[d][q]
    // staging: thread s stages phys chunk s; logical involution (verified)
    int l_ = tid ^ ((tid >> 3) & 7);
    const __bf16* kS = Kg + (l_ >> 2) * 32 + (l_ & 3) * 8;        // + m0*32
    const __bf16* vS = Vg + (long)(l_ >> 3) * N + (l_ & 7) * 8;   // + m0
    __bf16* kB = sMem;               // K bufs: 2 x 2048 elems
    __bf16* vB = sMem + 4096;        // V bufs: 2 x 2048 elems
    int so = wave * 512;
    auto STAGE = [&](long m0, int buf) {
        gload_lds16(kS + m0 * 32, kB + buf * 2048 + so);
        gload_lds16(vS + m0,      vB + buf * 2048 + so);
    };
    int pk[4], pvo[4][2];
    #pragma unroll
    for (int t = 0; t < 4; ++t) {
        int ck = (t * 16 + r) * 4 + g;
        pk[t] = (ck ^ ((ck >> 3) & 7)) * 8;
        #pragma unroll
        for (int dt = 0; dt < 2; ++dt) {
            int cv = (dt * 16 + r) * 8 + t * 2 + (g >> 1);
            pvo[t][dt] = (cv ^ ((cv >> 3) & 7)) * 8 + (g & 1) * 4;
        }
    }
    bf16x4 onesv;
    #pragma unroll
    for (int i = 0; i < 4; ++i) onesv[i] = (__bf16)1.0f;
    f32x4 oa0 = {}, oa1 = {}, oal = {};
    STAGE(0, 0);
    STAGE(64, 1);
    for (int t = 0; t < 18; ++t) {
        if (t < 17) { VMCNT2(); } else { VMCNT0(); }
        __builtin_amdgcn_s_barrier();        // tile t landed for all waves
        const __bf16* kb = kB + (t & 1) * 2048;
        const __bf16* vb = vB + (t & 1) * 2048;
        bf16x8 kc0 = load_bf8(kb + pk[0]);
        bf16x8 kc1 = load_bf8(kb + pk[1]);
        bf16x8 kc2 = load_bf8(kb + pk[2]);
        bf16x8 kc3 = load_bf8(kb + pk[3]);
        bf16x4 vf[4][2];
        #pragma unroll
        for (int tt = 0; tt < 4; ++tt)
            #pragma unroll
            for (int dt = 0; dt < 2; ++dt)
                vf[tt][dt] = *reinterpret_cast<const bf16x4*>(vb + pvo[tt][dt]);
        f32x4 z = {};
        __builtin_amdgcn_s_setprio(1);
        f32x4 s0 = mfma32(kc0, qf, z);   // S^T: lane(g,r) q=r, m=tt*16+g*4+i
        f32x4 s1 = mfma32(kc1, qf, z);
        f32x4 s2 = mfma32(kc2, qf, z);
        f32x4 s3 = mfma32(kc3, qf, z);
        __builtin_amdgcn_s_setprio(0);
        bf16x4 pa0, pa1, pa2, pa3;
        #pragma unroll
        for (int i = 0; i < 4; ++i) pa0[i] = (__bf16)EXP2F(s0[i]);
        #pragma unroll
        for (int i = 0; i < 4; ++i) pa1[i] = (__bf16)EXP2F(s1[i]);
        #pragma unroll
        for (int i = 0; i < 4; ++i) pa2[i] = (__bf16)EXP2F(s2[i]);
        #pragma unroll
        for (int i = 0; i < 4; ++i) pa3[i] = (__bf16)EXP2F(s3[i]);
        __builtin_amdgcn_s_setprio(1);
        oa0 = mfma16(vf[0][0], pa0, oa0);
        oa1 = mfma16(vf[0][1], pa0, oa1);
        oal = mfma16(onesv,    pa0, oal);
        oa0 = mfma16(vf[1][0], pa1, oa0);
        oa1 = mfma16(vf[1][1], pa1, oa1);
        oal = mfma16(onesv,    pa1, oal);
        oa0 = mfma16(vf[2][0], pa2, oa0);
        oa1 = mfma16(vf[2][1], pa2, oa1);
        oal = mfma16(onesv,    pa2, oal);
        oa0 = mfma16(vf[3][0], pa3, oa0);
        oa1 = mfma16(vf[3][1], pa3, oa1);
        oal = mfma16(onesv,    pa3, oal);
        __builtin_amdgcn_s_setprio(0);
        LGKM0();                             // my reads of this buffer done
        __builtin_amdgcn_s_barrier();        // everyone's reads done
        if (t < 16)                          // refill the buffer just consumed
            STAGE((long)(t + 2) * 64, t & 1);
    }
    // write f32 partials + per-head denominator (no combine here)
    long tok = (long)b * N + q0w + r;
    float* po = PO + ((long)half * T + tok) * 256 + h * 32 + g * 4;
    *reinterpret_cast<f32x4*>(po) = oa0;
    *reinterpret_cast<f32x4*>(po + 16) = oa1;
    if (g == 0) DO_[((long)half * T + tok) * 8 + h] = oal[0];
}

// ---------------- kernel 4: combine + output projection + bias + residual ----------------
__global__ __launch_bounds__(256) void outp_kernel(const __bf16* __restrict__ Wb,
    const float* __restrict__ PO, const float* __restrict__ DO_,
    const float* __restrict__ bo, const float* __restrict__ x,
    float* __restrict__ out) {
    __shared__ __bf16 sB[16 * 264 + 8];     // [16 tok][264 ch] padded
    int o0 = blockIdx.y * 64;
    int t0 = blockIdx.x * 16;
    int tid = threadIdx.x;
    // ---- stage: combine two key-half partials -> bf16 LDS tile ----
    {
        int qq = tid >> 4;                  // 0..15
        int cs = (tid & 15) * 16;           // channel start (within one head)
        int t = t0 + qq;
        int h = cs >> 5;
        float l = DO_[(long)t * 8 + h] + DO_[((long)T + t) * 8 + h];
        float inv = 1.0f / l;
        const float* p0 = PO + (long)t * 256 + cs;
        const float* p1 = PO + ((long)T + t) * 256 + cs;
        #pragma unroll
        for (int jj = 0; jj < 16; jj += 4) {
            f32x4 s = *reinterpret_cast<const f32x4*>(p0 + jj) +
                      *reinterpret_cast<const f32x4*>(p1 + jj);
            bf16x4 ov;
            #pragma unroll
            for (int i = 0; i < 4; ++i) ov[i] = (__bf16)(s[i] * inv);
            *reinterpret_cast<bf16x4*>(&sB[qq * 264 + cs + jj]) = ov;
        }
    }
    __syncthreads();
    int wave = tid >> 6, lane = tid & 63;
    int g = lane >> 4, r = lane & 15;
    int ow = o0 + wave * 16;
    const __bf16* W = Wb + 3 * 65536;   // Wo
    f32x4 acc = {};
    for (int k = 0; k < 8; ++k) {
        bf16x8 a = load_bf8(W + (ow + r) * C + k * 32 + g * 8);
        bf16x8 bfr = *reinterpret_cast<const bf16x8*>(&sB[r * 264 + k * 32 + g * 8]);
        acc = mfma32(a, bfr, acc);
    }
    float bvw[4];
    #pragma unroll
    for (int i = 0; i < 4; ++i) bvw[i] = bo[ow + g * 4 + i];
    int t = t0 + r;
    int b = t / N, n = t % N;
    #pragma unroll
    for (int i = 0; i < 4; ++i) {
        long idx = ((long)b * C + ow + g * 4 + i) * N + n;
        out[idx] = acc[i] + bvw[i] + x[idx];
    }
}

extern "C" void kernel_launch(void* const* d_in, const int* in_sizes, int n_in,
                              void* d_out, int out_size, void* d_ws, size_t ws_size,
                              hipStream_t stream) {
    const float* x  = (const float*)d_in[0];
    const float* u  = (const float*)d_in[1];
    const float* Wq = (const float*)d_in[2];
    const float* bq = (const float*)d_in[3];
    const float* Wk = (const float*)d_in[4];
    const float* bk = (const float*)d_in[5];
    const float* Wv = (const float*)d_in[6];
    const float* bv = (const float*)d_in[7];
    const float* Wg = (const float*)d_in[8];
    const float* bg = (const float*)d_in[9];
    const float* Wo = (const float*)d_in[10];
    const float* bo = (const float*)d_in[11];
    float* out = (float*)d_out;

    char* ws = (char*)d_ws;
    size_t off = 0;
    auto alloc = [&](size_t bytes) {
        char* p = ws + off;
        off += (bytes + 255) & ~(size_t)255;
        return p;
    };
    __bf16* Wb  = (__bf16*)alloc((size_t)4 * 65536 * 2);
    __bf16* xT  = (__bf16*)alloc((size_t)T * C * 2);
    __bf16* gxT = (__bf16*)alloc((size_t)T * C * 2);
    __bf16* Qb  = (__bf16*)alloc((size_t)16 * N * 32 * 2);
    __bf16* Kb  = (__bf16*)alloc((size_t)16 * N * 32 * 2);
    __bf16* Vb  = (__bf16*)alloc((size_t)16 * N * 32 * 2);
    float*  PO  = (float*)alloc((size_t)2 * T * 256 * 4);
    float*  DOp = (float*)alloc((size_t)2 * T * 8 * 4);

    prep_kernel<<<832, 256, 0, stream>>>(x, u, Wg, bg, Wq, Wk, Wv, Wo, xT, gxT, Wb);
    qkv_kernel<<<864, 256, 0, stream>>>(Wb, xT, gxT, bq, bk, bv, u, Qb, Kb, Vb);
    attn_kernel<<<1152, 256, 0, stream>>>(Qb, Kb, Vb, PO, DOp);
    outp_kernel<<<dim3(288, 4), 256, 0, stream>>>(Wb, PO, DOp, bo, x, out);
}